// Round 4
// baseline (125.156 us; speedup 1.0000x reference)
//
#include <hip/hip_runtime.h>
#include <math.h>

// DegreeQuantileConverter:
//   deg: (B,S,1) f32, q: (12,) f32 = [0,1,2,4,...,1024]
//   out: (B,S,12) f32 = log(w + 1e-30), w = linear-interp 2-hot row
//   (idx = searchsorted_right(q,deg)-1 clipped to [0,10]); whole row = 0.0f
//   (log(1+1e-30)) when deg >= q[11].
//
// Roofline: 100.7 MB write + 8.4 MB read -> ~17 us @ 6.3 TB/s achievable.
// Evidence trail: R1->R2 halved per-thread VALU, dur_us moved only -2.1%;
// kernel never appears in rocprof top-5 (all ~63us poison fills @6.3-6.5TB/s)
// -> kernel dispatch is small and ~memory-bound; bench dur_us is dominated by
// fixed harness re-poison/restore work.
// R4 change: R3 retry — nontemporal store via native clang vector type
// (__builtin_nontemporal_store rejects HIP_vector_type float4).
//
// Layout: one thread per output float4 (12%4==0 -> float4 never crosses a
// row), fully coalesced 16B stores; 3 adjacent lanes share one deg load.

#define KQ 12
#define LOG_EPS_F (-69.07755278982137f)  // logf(1e-30f)

typedef float vfloat4 __attribute__((ext_vector_type(4)));

__global__ __launch_bounds__(256) void dqc_kernel(
    const float* __restrict__ deg_in,
    const float* __restrict__ q,
    vfloat4* __restrict__ out,
    unsigned nvec)
{
    unsigned t = blockIdx.x * 256u + threadIdx.x;
    if (t >= nvec) return;

    unsigned row  = t / 3u;            // magic-mul div by 3
    unsigned part = t - row * 3u;      // which float4 of the row (0..2)

    float deg = deg_in[row];

    float qv[KQ];
#pragma unroll
    for (int i = 0; i < KQ; ++i) qv[i] = q[i];   // uniform addrs -> s_load

    // searchsorted(q, deg, 'right') - 1, clipped to [0, KQ-2]
    int   idx = 0;
    float lo  = qv[0];
    float hi  = qv[1];
#pragma unroll
    for (int i = 1; i <= KQ - 2; ++i) {
        bool ge = (deg >= qv[i]);
        idx = ge ? i : idx;
        lo  = ge ? qv[i]     : lo;
        hi  = ge ? qv[i + 1] : hi;
    }

    // pos = clamp((deg-lo)*rcp(hi-lo+1e-10), 0, 1); rcp is 1-ulp, divisor is
    // 2^k + 1e-10 -> error negligible vs the 1.38 absmax threshold
    float pos = (deg - lo) * __builtin_amdgcn_rcpf(hi - lo + 1e-10f);
    pos = fminf(fmaxf(pos, 0.0f), 1.0f);   // v_med3

    bool in_range = (deg >= qv[0]) && (deg < qv[KQ - 1]);
    bool top      = (deg >= qv[KQ - 1]);   // whole row -> log(1+1e-30) == 0.0f

    float w_lo = in_range ? (1.0f - pos) : 0.0f;
    float w_hi = in_range ? pos          : 0.0f;
    float lw_lo = __logf(w_lo + 1e-30f);   // v_log_f32 * ln2
    float lw_hi = __logf(w_hi + 1e-30f);
    float fill  = LOG_EPS_F;
    if (top) { lw_lo = 0.0f; lw_hi = 0.0f; fill = 0.0f; }  // 3 cndmasks

    int j0 = (int)part * 4;
    vfloat4 o;
#pragma unroll
    for (int u = 0; u < 4; ++u) {
        int j = j0 + u;
        o[u] = (j == idx) ? lw_lo : ((j == idx + 1) ? lw_hi : fill);
    }

    __builtin_nontemporal_store(o, &out[t]);   // global_store_dwordx4 ... nt

}

extern "C" void kernel_launch(void* const* d_in, const int* in_sizes, int n_in,
                              void* d_out, int out_size, void* d_ws, size_t ws_size,
                              hipStream_t stream) {
    const float* deg = (const float*)d_in[0];  // (B*S,) flat, 2,097,152
    const float* q   = (const float*)d_in[1];  // (12,)
    vfloat4* out     = (vfloat4*)d_out;        // (B*S*12,) f32, 12%4==0

    unsigned nvec = (unsigned)(out_size / 4);  // 6,291,456 float4s
    unsigned blocks = (nvec + 255u) / 256u;

    dqc_kernel<<<blocks, 256, 0, stream>>>(deg, q, out, nvec);
}

// Round 5
// 120.879 us; speedup vs baseline: 1.0354x; 1.0354x over previous
//
#include <hip/hip_runtime.h>
#include <math.h>

// DegreeQuantileConverter:
//   deg: (B,S,1) f32, q: (12,) f32 = [0,1,2,4,...,1024]
//   out: (B,S,12) f32 = log(w + 1e-30), w = linear-interp 2-hot row
//   (idx = searchsorted_right(q,deg)-1 clipped to [0,10]); whole row = 0.0f
//   (log(1+1e-30)) when deg >= q[11].
//
// FINAL (R5 = revert to R2, the best-measured variant):
//   Roofline: 100.7 MB write + 8.4 MB read -> ~17.3 us @ measured 6.3 TB/s.
//   Kernel dispatch is ~18-22 us (never appears in rocprof top-5; cutoff
//   ~63 us — all five slots are the harness's 402 MB re-poison fills).
//   bench dur_us (~119) is dominated by harness-fixed work: 63 us poison
//   fill + input restore + replay overhead. Evidence: 2x VALU cut (R1->R2)
//   moved dur_us only -2.1%; NT-store (R4) was neutral-to-negative (+5%,
//   within session noise of the fills' own 2% drift). VALU issue arithmetic:
//   80 instr/thread x 6.29M threads / 64 lanes x 2 cy / 1024 SIMDs = 6.4 us
//   << 16 us store time -> memory-bound at the write ceiling.
//
// Layout: one thread per output float4 (12%4==0 -> a float4 never crosses a
// row boundary) -> fully coalesced aligned 16B stores, consecutive lanes ->
// consecutive addresses (same pattern as the 6.4 TB/s fill kernel).
// 3 adjacent lanes share one deg load (L1 broadcast).

#define KQ 12
#define LOG_EPS_F (-69.07755278982137f)  // logf(1e-30f)

__global__ __launch_bounds__(256) void dqc_kernel(
    const float* __restrict__ deg_in,
    const float* __restrict__ q,
    float4* __restrict__ out,
    unsigned nvec)
{
    unsigned t = blockIdx.x * 256u + threadIdx.x;
    if (t >= nvec) return;

    unsigned row  = t / 3u;            // magic-mul div by 3
    unsigned part = t - row * 3u;      // which float4 of the row (0..2)

    float deg = deg_in[row];

    float qv[KQ];
#pragma unroll
    for (int i = 0; i < KQ; ++i) qv[i] = q[i];   // uniform addrs -> s_load

    // searchsorted(q, deg, 'right') - 1, clipped to [0, KQ-2]
    int   idx = 0;
    float lo  = qv[0];
    float hi  = qv[1];
#pragma unroll
    for (int i = 1; i <= KQ - 2; ++i) {
        bool ge = (deg >= qv[i]);
        idx = ge ? i : idx;
        lo  = ge ? qv[i]     : lo;
        hi  = ge ? qv[i + 1] : hi;
    }

    // pos = clamp((deg-lo)*rcp(hi-lo+1e-10), 0, 1); v_rcp_f32 is 1-ulp and
    // the divisor is 2^k + 1e-10 -> error negligible vs 1.38 absmax threshold
    float pos = (deg - lo) * __builtin_amdgcn_rcpf(hi - lo + 1e-10f);
    pos = fminf(fmaxf(pos, 0.0f), 1.0f);   // v_med3

    bool in_range = (deg >= qv[0]) && (deg < qv[KQ - 1]);
    bool top      = (deg >= qv[KQ - 1]);   // whole row -> log(1+1e-30) == 0.0f

    float w_lo = in_range ? (1.0f - pos) : 0.0f;
    float w_hi = in_range ? pos          : 0.0f;
    float lw_lo = __logf(w_lo + 1e-30f);   // v_log_f32 * ln2
    float lw_hi = __logf(w_hi + 1e-30f);
    float fill  = LOG_EPS_F;
    if (top) { lw_lo = 0.0f; lw_hi = 0.0f; fill = 0.0f; }  // 3 cndmasks

    int j0 = (int)part * 4;
    float v[4];
#pragma unroll
    for (int u = 0; u < 4; ++u) {
        int j = j0 + u;
        v[u] = (j == idx) ? lw_lo : ((j == idx + 1) ? lw_hi : fill);
    }

    float4 o;
    o.x = v[0]; o.y = v[1]; o.z = v[2]; o.w = v[3];
    out[t] = o;
}

extern "C" void kernel_launch(void* const* d_in, const int* in_sizes, int n_in,
                              void* d_out, int out_size, void* d_ws, size_t ws_size,
                              hipStream_t stream) {
    const float* deg = (const float*)d_in[0];  // (B*S,) flat, 2,097,152
    const float* q   = (const float*)d_in[1];  // (12,)
    float4* out      = (float4*)d_out;         // (B*S*12,) f32, 12%4==0

    unsigned nvec = (unsigned)(out_size / 4);  // 6,291,456 float4s
    unsigned blocks = (nvec + 255u) / 256u;

    dqc_kernel<<<blocks, 256, 0, stream>>>(deg, q, out, nvec);
}